// Round 17
// baseline (116.522 us; speedup 1.0000x reference)
//
#include <hip/hip_runtime.h>

#define C_NUM    256
#define KCODES   4096
#define THREADS  1024
#define CHUNK    1024
#define NCHUNK   4
#define AROW     68               // 17-word row stride: 16 lane-starts all-distinct banks
#define MARGIN   0.125f           // >> worst-case approx+trunc error (~0.03); R16-validated

// LDS layout (bytes)
#define OFF_A    0                               // 1024 * 68 = 69632
#define OFF_XS   (CHUNK * AROW)                  // 69632 : float xs[128][8]
#define OFF_M1   (OFF_XS + 4096)                 // 73728 : u32 m1sh[16][16]
#define OFF_M2   (OFF_M1 + 1024)                 // 74752 : u32 m2sh[16][16]
#define OFF_BEST (OFF_M2 + 1024)                 // 75776 : int best[128]
#define OFF_UL   (OFF_BEST + 512)                // 76288 : int ulist[128]
#define OFF_NU   (OFF_UL + 512)                  // 76800 : int nu
#define SMEM_SZ  (OFF_NU + 16)                   // 76816

typedef short  bf16x8 __attribute__((ext_vector_type(8)));
typedef float  f32x4  __attribute__((ext_vector_type(4)));
typedef float  v4f    __attribute__((ext_vector_type(4)));

__device__ __forceinline__ unsigned short bf16rn(float f) {
    unsigned u = __float_as_uint(f);
    u += 0x7FFFu + ((u >> 16) & 1u);
    return (unsigned short)(u >> 16);
}
__device__ __forceinline__ float bf16tof(unsigned short h) {
    return __uint_as_float(((unsigned)h) << 16);
}
__device__ __forceinline__ unsigned umin(unsigned a, unsigned b) { return a < b ? a : b; }
__device__ __forceinline__ unsigned umax(unsigned a, unsigned b) { return a > b ? a : b; }

__global__ __launch_bounds__(THREADS)
void dkvb_kernel(const float* __restrict__ emb,
                 const float* __restrict__ keys,
                 const float* __restrict__ values,
                 float* __restrict__ out) {
    extern __shared__ unsigned char sm[];
    float (*xs)[8]  = (float(*)[8])(sm + OFF_XS);
    unsigned* m1sh  = (unsigned*)(sm + OFF_M1);
    unsigned* m2sh  = (unsigned*)(sm + OFF_M2);
    int* best  = (int*)(sm + OFF_BEST);
    int* ulist = (int*)(sm + OFF_UL);
    int* nu    = (int*)(sm + OFF_NU);

    const int c    = blockIdx.x;          // one codebook per block
    const int tid  = threadIdx.x;
    const int wave = tid >> 6;
    const int lane = tid & 63;
    const int wt   = wave & 7;            // tuple-tile (16 tuples)
    const int half = wave >> 3;           // tile-half of each chunk (0: tiles 0-31, 1: 32-63)
    const int col  = lane & 15;
    const int g    = lane >> 4;
    const int arow = lane & 15;

    const v4f* kb4 = (const v4f*)(keys + (size_t)c * KCODES * 8);

    if (tid == 0) *nu = 0;

    // ---- stage x: 1 element/thread. xs[t][j] = emb[(t>>4)*32768 + c*128 + j*16 + (t&15)] ----
    {
        const int t = tid >> 3, j = tid & 7;
        xs[t][j] = emb[(size_t)(t >> 4) * 32768 + c * 128 + j * 16 + (t & 15)];
    }
    __syncthreads();

    // ---- B-frag for this wave's 16 tuples ----
    // k-slots: [0-7: xh | 8-15: xh | 16-23: xl | 24:1 25:1 26:x2h 27:x2l 28-31:0]
    bf16x8 bfrag;
    {
        const int t = wt * 16 + col;
        float xv[8];
        #pragma unroll
        for (int j = 0; j < 8; ++j) xv[j] = xs[t][j];
        float x2 = xv[0] * xv[0];
        #pragma unroll
        for (int j = 1; j < 8; ++j) x2 = fmaf(xv[j], xv[j], x2);
        bf16x8 fxh, fxl, fct;
        #pragma unroll
        for (int j = 0; j < 8; ++j) {
            const unsigned short hh = bf16rn(xv[j]);
            fxh[j] = (short)hh;
            fxl[j] = (short)bf16rn(xv[j] - bf16tof(hh));
        }
        const unsigned short x2h = bf16rn(x2);
        const unsigned short x2l = bf16rn(x2 - bf16tof(x2h));
        fct[0] = (short)0x3F80; fct[1] = (short)0x3F80;
        fct[2] = (short)x2h;    fct[3] = (short)x2l;
        fct[4] = 0; fct[5] = 0; fct[6] = 0; fct[7] = 0;
        bfrag = (g < 2) ? fxh : ((g == 2) ? fxl : fct);
    }

    const f32x4 zeroC = {0.f, 0.f, 0.f, 0.f};
    unsigned m1 = 0xFFFFFFFFu, m2 = 0xFFFFFFFFu;
    const int tbase = half * 32;

    // ---- 4 chunks: convert 1024 codes -> LDS A-frags; wave-halves split the tiles ----
    for (int ph = 0; ph < NCHUNK; ++ph) {
        const int cbase = ph * CHUNK;

        // convert: 1 code/thread. A k-slots:
        // [0-7: -2kh | 8-15: -2kl | 16-23: -2kh | 24:k2h 25:k2l 26:1 27:1 28-31:0]
        {
            const int ci   = tid;
            const int code = cbase + ci;
            const v4f p0 = kb4[code * 2];
            const v4f p1 = kb4[code * 2 + 1];
            float kk[8] = {p0.x, p0.y, p0.z, p0.w, p1.x, p1.y, p1.z, p1.w};
            float k2 = kk[0] * kk[0];
            #pragma unroll
            for (int j = 1; j < 8; ++j) k2 = fmaf(kk[j], kk[j], k2);
            unsigned short th[8], tl[8];
            #pragma unroll
            for (int j = 0; j < 8; ++j) {
                const float tt = -2.0f * kk[j];
                th[j] = bf16rn(tt);
                tl[j] = bf16rn(tt - bf16tof(th[j]));
            }
            const unsigned short k2h = bf16rn(k2);
            const unsigned short k2l = bf16rn(k2 - bf16tof(k2h));
            unsigned w[16];
            #pragma unroll
            for (int i = 0; i < 4; ++i) w[i]     = (unsigned)th[2*i] | ((unsigned)th[2*i+1] << 16);
            #pragma unroll
            for (int i = 0; i < 4; ++i) w[4 + i] = (unsigned)tl[2*i] | ((unsigned)tl[2*i+1] << 16);
            #pragma unroll
            for (int i = 0; i < 4; ++i) w[8 + i] = w[i];
            w[12] = (unsigned)k2h | ((unsigned)k2l << 16);
            w[13] = 0x3F803F80u;
            w[14] = 0u; w[15] = 0u;
            uint4* dst = (uint4*)(sm + OFF_A + (size_t)ci * AROW);
            dst[0] = make_uint4(w[0],  w[1],  w[2],  w[3]);
            dst[1] = make_uint4(w[4],  w[5],  w[6],  w[7]);
            dst[2] = make_uint4(w[8],  w[9],  w[10], w[11]);
            dst[3] = make_uint4(w[12], w[13], w[14], w[15]);
        }
        __syncthreads();

        // scan this wave-half's 32 tiles, unroll x2 (independent MFMA chains)
        const unsigned char* abase = sm + OFF_A + (size_t)(tbase * 16 + arow) * AROW + (size_t)g * 16;
        for (int tile = 0; tile < 32; tile += 2) {
            const bf16x8 af0 = *(const bf16x8*)(abase + (size_t)tile * (16 * AROW));
            const bf16x8 af1 = *(const bf16x8*)(abase + (size_t)(tile + 1) * (16 * AROW));
            const f32x4 D0 = __builtin_amdgcn_mfma_f32_16x16x32_bf16(af0, bfrag, zeroC, 0, 0, 0);
            const f32x4 D1 = __builtin_amdgcn_mfma_f32_16x16x32_bf16(af1, bfrag, zeroC, 0, 0, 0);
            const int cb0 = cbase + (tbase + tile) * 16 + g * 4;
            #pragma unroll
            for (int r2 = 0; r2 < 4; ++r2) {
                const unsigned key = (__float_as_uint(D0[r2]) & 0xFFFFF000u) | (unsigned)(cb0 + r2);
                m2 = umin(m2, umax(m1, key));
                m1 = umin(m1, key);
            }
            #pragma unroll
            for (int r2 = 0; r2 < 4; ++r2) {
                const unsigned key = (__float_as_uint(D1[r2]) & 0xFFFFF000u) | (unsigned)(cb0 + 16 + r2);
                m2 = umin(m2, umax(m1, key));
                m1 = umin(m1, key);
            }
        }
        __syncthreads();   // scan done before next chunk's convert overwrites A
    }

    // ---- reduce (m1,m2) across the 4 row-groups sharing each column ----
    #pragma unroll
    for (int sh = 16; sh <= 32; sh <<= 1) {
        const unsigned o1 = (unsigned)__shfl_xor((int)m1, sh, 64);
        const unsigned o2 = (unsigned)__shfl_xor((int)m2, sh, 64);
        const unsigned hi = umax(m1, o1);
        m1 = umin(m1, o1);
        m2 = umin(umin(m2, o2), hi);
    }
    if (lane < 16) { m1sh[wave * 16 + lane] = m1; m2sh[wave * 16 + lane] = m2; }
    __syncthreads();

    // ---- merge the two wave-halves (disjoint code ranges) ----
    if (wave < 8 && lane < 16) {
        const unsigned a1 = m1sh[wave * 16 + lane];
        const unsigned a2 = m2sh[wave * 16 + lane];
        const unsigned b1 = m1sh[(wave + 8) * 16 + lane];
        const unsigned b2 = m2sh[(wave + 8) * 16 + lane];
        const unsigned M1 = umin(a1, b1);
        const unsigned M2 = umin(umin(a2, b2), umax(a1, b1));
        const int t = wave * 16 + lane;
        best[t] = (int)(M1 & 0xFFFu);
        const float v1 = __uint_as_float(M1 & 0xFFFFF000u);
        const float v2 = __uint_as_float(M2 & 0xFFFFF000u);
        if (v2 - v1 < MARGIN) {            // not provably separated -> exact rescan
            const int idx = atomicAdd(nu, 1);
            ulist[idx] = t;
        }
    }
    __syncthreads();

    // ---- exact refine (rare): full fp32 scan with the R14-proven chain ----
    const int NU = *nu;
    for (int e = wave; e < NU; e += 16) {
        const int t = ulist[e];
        float xp[8];
        #pragma unroll
        for (int j = 0; j < 8; ++j) xp[j] = -2.0f * xs[t][j];
        float bd = 3.4028235e38f;
        int   bi = 0;
        for (int it = 0; it < 64; ++it) {
            const int code = it * 64 + lane;
            const v4f p0 = kb4[code * 2];
            const v4f p1 = kb4[code * 2 + 1];
            float k2 = p0.x * p0.x;
            k2 = fmaf(p0.y, p0.y, k2);
            k2 = fmaf(p0.z, p0.z, k2);
            k2 = fmaf(p0.w, p0.w, k2);
            k2 = fmaf(p1.x, p1.x, k2);
            k2 = fmaf(p1.y, p1.y, k2);
            k2 = fmaf(p1.z, p1.z, k2);
            k2 = fmaf(p1.w, p1.w, k2);
            float d = fmaf(xp[0], p0.x, k2);
            d = fmaf(xp[1], p0.y, d);
            d = fmaf(xp[2], p0.z, d);
            d = fmaf(xp[3], p0.w, d);
            d = fmaf(xp[4], p1.x, d);
            d = fmaf(xp[5], p1.y, d);
            d = fmaf(xp[6], p1.z, d);
            d = fmaf(xp[7], p1.w, d);
            if (d < bd) { bd = d; bi = code; }   // ascending order -> numpy tie-break
        }
        #pragma unroll
        for (int msk = 32; msk >= 1; msk >>= 1) {
            const float od = __shfl_xor(bd, msk, 64);
            const int   oi = __shfl_xor(bi, msk, 64);
            if (od < bd || (od == bd && oi < bi)) { bd = od; bi = oi; }
        }
        if (lane == 0) best[t] = bi;
    }
    __syncthreads();

    // ---- gather values + scatter output ----
    if (tid < 128) {
        const int t = tid;
        const int code = best[t];
        const v4f* vr = (const v4f*)(values + ((size_t)c * KCODES + code) * 8);
        const v4f v0 = vr[0];
        const v4f v1 = vr[1];
        float* op = out + (size_t)(t >> 4) * 32768 + c * 128 + (t & 15);
        op[0]   = v0.x; op[16]  = v0.y; op[32]  = v0.z; op[48]  = v0.w;
        op[64]  = v1.x; op[80]  = v1.y; op[96]  = v1.z; op[112] = v1.w;
    }
}

extern "C" void kernel_launch(void* const* d_in, const int* in_sizes, int n_in,
                              void* d_out, int out_size, void* d_ws, size_t ws_size,
                              hipStream_t stream) {
    const float* emb    = (const float*)d_in[0];
    const float* keys   = (const float*)d_in[1];
    const float* values = (const float*)d_in[2];
    float* out = (float*)d_out;

    hipFuncSetAttribute((const void*)dkvb_kernel,
                        hipFuncAttributeMaxDynamicSharedMemorySize, SMEM_SZ);
    dkvb_kernel<<<C_NUM, THREADS, SMEM_SZ, stream>>>(emb, keys, values, out);
}

// Round 18
// 76.149 us; speedup vs baseline: 1.5302x; 1.5302x over previous
//
#include <hip/hip_runtime.h>

#define C_NUM    256
#define KCODES   4096
#define THREADS  1024
#define CHUNK    1024
#define NCHUNK   4
#define AROW     80               // 16B-aligned rows; 20*arow%32 start pattern = 2-way (free, m136)
#define MARGIN   0.125f           // >> worst-case approx+trunc error (~0.03); validated R16/R17

// LDS layout (bytes)
#define OFF_A    0                               // 1024 * 80 = 81920
#define OFF_XS   (CHUNK * AROW)                  // 81920 : float xs[128][8]
#define OFF_M1   (OFF_XS + 4096)                 // 86016 : u32 m1sh[16][16]
#define OFF_M2   (OFF_M1 + 1024)                 // 87040 : u32 m2sh[16][16]
#define OFF_BEST (OFF_M2 + 1024)                 // 88064 : int best[128]
#define OFF_UL   (OFF_BEST + 512)                // 88576 : int ulist[128]
#define OFF_NU   (OFF_UL + 512)                  // 89088 : int nu
#define SMEM_SZ  (OFF_NU + 16)                   // 89104

typedef short  bf16x8 __attribute__((ext_vector_type(8)));
typedef float  f32x4  __attribute__((ext_vector_type(4)));
typedef float  v4f    __attribute__((ext_vector_type(4)));

__device__ __forceinline__ unsigned short bf16rn(float f) {
    unsigned u = __float_as_uint(f);
    u += 0x7FFFu + ((u >> 16) & 1u);
    return (unsigned short)(u >> 16);
}
__device__ __forceinline__ float bf16tof(unsigned short h) {
    return __uint_as_float(((unsigned)h) << 16);
}
__device__ __forceinline__ unsigned umn(unsigned a, unsigned b) { return a < b ? a : b; }
__device__ __forceinline__ unsigned umx(unsigned a, unsigned b) { return a > b ? a : b; }

__global__ __launch_bounds__(THREADS)
void dkvb_kernel(const float* __restrict__ emb,
                 const float* __restrict__ keys,
                 const float* __restrict__ values,
                 float* __restrict__ out) {
    extern __shared__ unsigned char sm[];
    float (*xs)[8]  = (float(*)[8])(sm + OFF_XS);
    unsigned* m1sh  = (unsigned*)(sm + OFF_M1);
    unsigned* m2sh  = (unsigned*)(sm + OFF_M2);
    int* best  = (int*)(sm + OFF_BEST);
    int* ulist = (int*)(sm + OFF_UL);
    int* nu    = (int*)(sm + OFF_NU);

    const int c    = blockIdx.x;          // one codebook per block
    const int tid  = threadIdx.x;
    const int wave = tid >> 6;
    const int lane = tid & 63;
    const int wt   = wave & 7;            // tuple-tile (16 tuples)
    const int half = wave >> 3;           // tile-half of each chunk (0: tiles 0-31, 1: 32-63)
    const int col  = lane & 15;
    const int g    = lane >> 4;
    const int arow = lane & 15;

    const v4f* kb4 = (const v4f*)(keys + (size_t)c * KCODES * 8);

    if (tid == 0) *nu = 0;

    // ---- stage x: 1 element/thread. xs[t][j] = emb[(t>>4)*32768 + c*128 + j*16 + (t&15)] ----
    {
        const int t = tid >> 3, j = tid & 7;
        xs[t][j] = emb[(size_t)(t >> 4) * 32768 + c * 128 + j * 16 + (t & 15)];
    }
    __syncthreads();

    // ---- B-frag for this wave's 16 tuples ----
    // k-slots: [0-7: xh | 8-15: xh | 16-23: xl | 24:1 25:1 26:x2h 27:x2l 28-31:0]
    bf16x8 bfrag;
    {
        const int t = wt * 16 + col;
        float xv[8];
        #pragma unroll
        for (int j = 0; j < 8; ++j) xv[j] = xs[t][j];
        float x2 = xv[0] * xv[0];
        #pragma unroll
        for (int j = 1; j < 8; ++j) x2 = fmaf(xv[j], xv[j], x2);
        bf16x8 fxh, fxl, fct;
        #pragma unroll
        for (int j = 0; j < 8; ++j) {
            const unsigned short hh = bf16rn(xv[j]);
            fxh[j] = (short)hh;
            fxl[j] = (short)bf16rn(xv[j] - bf16tof(hh));
        }
        const unsigned short x2h = bf16rn(x2);
        const unsigned short x2l = bf16rn(x2 - bf16tof(x2h));
        fct[0] = (short)0x3F80; fct[1] = (short)0x3F80;
        fct[2] = (short)x2h;    fct[3] = (short)x2l;
        fct[4] = 0; fct[5] = 0; fct[6] = 0; fct[7] = 0;
        bfrag = (g < 2) ? fxh : ((g == 2) ? fxl : fct);
    }

    const f32x4 zeroC = {0.f, 0.f, 0.f, 0.f};
    unsigned m1a = 0xFFFFFFFFu, m2a = 0xFFFFFFFFu;   // even-tile tracker
    unsigned m1b = 0xFFFFFFFFu, m2b = 0xFFFFFFFFu;   // odd-tile tracker
    const int tbase = half * 32;

    // ---- 4 chunks: convert 1024 codes -> LDS A-frags; wave-halves split the tiles ----
    for (int ph = 0; ph < NCHUNK; ++ph) {
        const int cbase = ph * CHUNK;

        // convert: 1 code/thread. A k-slots:
        // [0-7: -2kh | 8-15: -2kl | 16-23: -2kh | 24:k2h 25:k2l 26:1 27:1 28-31:0]
        {
            const int ci   = tid;
            const int code = cbase + ci;
            const v4f p0 = kb4[code * 2];
            const v4f p1 = kb4[code * 2 + 1];
            float kk[8] = {p0.x, p0.y, p0.z, p0.w, p1.x, p1.y, p1.z, p1.w};
            float k2 = kk[0] * kk[0];
            #pragma unroll
            for (int j = 1; j < 8; ++j) k2 = fmaf(kk[j], kk[j], k2);
            unsigned short th[8], tl[8];
            #pragma unroll
            for (int j = 0; j < 8; ++j) {
                const float tt = -2.0f * kk[j];
                th[j] = bf16rn(tt);
                tl[j] = bf16rn(tt - bf16tof(th[j]));
            }
            const unsigned short k2h = bf16rn(k2);
            const unsigned short k2l = bf16rn(k2 - bf16tof(k2h));
            unsigned w[16];
            #pragma unroll
            for (int i = 0; i < 4; ++i) w[i]     = (unsigned)th[2*i] | ((unsigned)th[2*i+1] << 16);
            #pragma unroll
            for (int i = 0; i < 4; ++i) w[4 + i] = (unsigned)tl[2*i] | ((unsigned)tl[2*i+1] << 16);
            #pragma unroll
            for (int i = 0; i < 4; ++i) w[8 + i] = w[i];
            w[12] = (unsigned)k2h | ((unsigned)k2l << 16);
            w[13] = 0x3F803F80u;
            w[14] = 0u; w[15] = 0u;
            uint4* dst = (uint4*)(sm + OFF_A + (size_t)ci * AROW);
            dst[0] = make_uint4(w[0],  w[1],  w[2],  w[3]);
            dst[1] = make_uint4(w[4],  w[5],  w[6],  w[7]);
            dst[2] = make_uint4(w[8],  w[9],  w[10], w[11]);
            dst[3] = make_uint4(w[12], w[13], w[14], w[15]);
        }
        __syncthreads();

        // scan this wave-half's 32 tiles; x2 unroll with INDEPENDENT trackers
        const unsigned char* abase = sm + OFF_A + (size_t)(tbase * 16 + arow) * AROW + (size_t)g * 16;
        for (int tile = 0; tile < 32; tile += 2) {
            const bf16x8 af0 = *(const bf16x8*)(abase + (size_t)tile * (16 * AROW));
            const bf16x8 af1 = *(const bf16x8*)(abase + (size_t)(tile + 1) * (16 * AROW));
            const f32x4 D0 = __builtin_amdgcn_mfma_f32_16x16x32_bf16(af0, bfrag, zeroC, 0, 0, 0);
            const f32x4 D1 = __builtin_amdgcn_mfma_f32_16x16x32_bf16(af1, bfrag, zeroC, 0, 0, 0);
            const int cb0 = cbase + (tbase + tile) * 16 + g * 4;
            #pragma unroll
            for (int r2 = 0; r2 < 4; ++r2) {
                const unsigned key = (__float_as_uint(D0[r2]) & 0xFFFFF000u) | (unsigned)(cb0 + r2);
                m2a = umn(m2a, umx(m1a, key));
                m1a = umn(m1a, key);
            }
            #pragma unroll
            for (int r2 = 0; r2 < 4; ++r2) {
                const unsigned key = (__float_as_uint(D1[r2]) & 0xFFFFF000u) | (unsigned)(cb0 + 16 + r2);
                m2b = umn(m2b, umx(m1b, key));
                m1b = umn(m1b, key);
            }
        }
        __syncthreads();   // scan done before next chunk's convert overwrites A
    }

    // ---- merge even/odd trackers (disjoint code sets) ----
    unsigned m1 = umn(m1a, m1b);
    unsigned m2 = umn(umx(m1a, m1b), umn(m2a, m2b));

    // ---- reduce (m1,m2) across the 4 row-groups sharing each column ----
    #pragma unroll
    for (int sh = 16; sh <= 32; sh <<= 1) {
        const unsigned o1 = (unsigned)__shfl_xor((int)m1, sh, 64);
        const unsigned o2 = (unsigned)__shfl_xor((int)m2, sh, 64);
        const unsigned hi = umx(m1, o1);
        m1 = umn(m1, o1);
        m2 = umn(umn(m2, o2), hi);
    }
    if (lane < 16) { m1sh[wave * 16 + lane] = m1; m2sh[wave * 16 + lane] = m2; }
    __syncthreads();

    // ---- merge the two wave-halves (disjoint code ranges) ----
    if (wave < 8 && lane < 16) {
        const unsigned a1 = m1sh[wave * 16 + lane];
        const unsigned a2 = m2sh[wave * 16 + lane];
        const unsigned b1 = m1sh[(wave + 8) * 16 + lane];
        const unsigned b2 = m2sh[(wave + 8) * 16 + lane];
        const unsigned M1 = umn(a1, b1);
        const unsigned M2 = umn(umn(a2, b2), umx(a1, b1));
        const int t = wave * 16 + lane;
        best[t] = (int)(M1 & 0xFFFu);
        const float v1 = __uint_as_float(M1 & 0xFFFFF000u);
        const float v2 = __uint_as_float(M2 & 0xFFFFF000u);
        if (v2 - v1 < MARGIN) {            // not provably separated -> exact rescan
            const int idx = atomicAdd(nu, 1);
            ulist[idx] = t;
        }
    }
    __syncthreads();

    // ---- exact refine (rare): full fp32 scan with the R14-proven chain ----
    const int NU = *nu;
    for (int e = wave; e < NU; e += 16) {
        const int t = ulist[e];
        float xp[8];
        #pragma unroll
        for (int j = 0; j < 8; ++j) xp[j] = -2.0f * xs[t][j];
        float bd = 3.4028235e38f;
        int   bi = 0;
        for (int it = 0; it < 64; ++it) {
            const int code = it * 64 + lane;
            const v4f p0 = kb4[code * 2];
            const v4f p1 = kb4[code * 2 + 1];
            float k2 = p0.x * p0.x;
            k2 = fmaf(p0.y, p0.y, k2);
            k2 = fmaf(p0.z, p0.z, k2);
            k2 = fmaf(p0.w, p0.w, k2);
            k2 = fmaf(p1.x, p1.x, k2);
            k2 = fmaf(p1.y, p1.y, k2);
            k2 = fmaf(p1.z, p1.z, k2);
            k2 = fmaf(p1.w, p1.w, k2);
            float d = fmaf(xp[0], p0.x, k2);
            d = fmaf(xp[1], p0.y, d);
            d = fmaf(xp[2], p0.z, d);
            d = fmaf(xp[3], p0.w, d);
            d = fmaf(xp[4], p1.x, d);
            d = fmaf(xp[5], p1.y, d);
            d = fmaf(xp[6], p1.z, d);
            d = fmaf(xp[7], p1.w, d);
            if (d < bd) { bd = d; bi = code; }   // ascending order -> numpy tie-break
        }
        #pragma unroll
        for (int msk = 32; msk >= 1; msk >>= 1) {
            const float od = __shfl_xor(bd, msk, 64);
            const int   oi = __shfl_xor(bi, msk, 64);
            if (od < bd || (od == bd && oi < bi)) { bd = od; bi = oi; }
        }
        if (lane == 0) best[t] = bi;
    }
    __syncthreads();

    // ---- gather values + scatter output ----
    if (tid < 128) {
        const int t = tid;
        const int code = best[t];
        const v4f* vr = (const v4f*)(values + ((size_t)c * KCODES + code) * 8);
        const v4f v0 = vr[0];
        const v4f v1 = vr[1];
        float* op = out + (size_t)(t >> 4) * 32768 + c * 128 + (t & 15);
        op[0]   = v0.x; op[16]  = v0.y; op[32]  = v0.z; op[48]  = v0.w;
        op[64]  = v1.x; op[80]  = v1.y; op[96]  = v1.z; op[112] = v1.w;
    }
}

extern "C" void kernel_launch(void* const* d_in, const int* in_sizes, int n_in,
                              void* d_out, int out_size, void* d_ws, size_t ws_size,
                              hipStream_t stream) {
    const float* emb    = (const float*)d_in[0];
    const float* keys   = (const float*)d_in[1];
    const float* values = (const float*)d_in[2];
    float* out = (float*)d_out;

    hipFuncSetAttribute((const void*)dkvb_kernel,
                        hipFuncAttributeMaxDynamicSharedMemorySize, SMEM_SZ);
    dkvb_kernel<<<C_NUM, THREADS, SMEM_SZ, stream>>>(emb, keys, values, out);
}

// Round 19
// 44.895 us; speedup vs baseline: 2.5955x; 1.6962x over previous
//
#include <hip/hip_runtime.h>

#define C_NUM   256
#define K_CODES 4096
#define D_CB    8
#define THREADS 512
#define TPW     8                   // tuples per wave; 8 waves x 8 = 64 tuples/block
#define CHUNKS  64                  // every wave scans all 4096 codes, 64/chunk

typedef float v2f __attribute__((ext_vector_type(2)));

// packed fp32 FMA: d = x * bcast(key) + d, tuple-pair in the two halves.
// op_sel[i]/op_sel_hi[i] pick the src word for the low/high result half.
#define PK_INIT(d, x, kp, c) \
    asm("v_pk_fma_f32 %0, %1, %2, %3 op_sel:[0,0,0] op_sel_hi:[1,0,1]" \
        : "=v"(d) : "v"(x), "v"(kp), "v"(c))
#define PK_LO(d, x, kp) \
    asm("v_pk_fma_f32 %0, %1, %2, %0 op_sel:[0,0,0] op_sel_hi:[1,0,1]" \
        : "+v"(d) : "v"(x), "v"(kp))
#define PK_HI(d, x, kp) \
    asm("v_pk_fma_f32 %0, %1, %2, %0 op_sel:[0,1,0] op_sel_hi:[1,1,1]" \
        : "+v"(d) : "v"(x), "v"(kp))

__global__ __launch_bounds__(THREADS, 2)   // min-waves=2; larger values wreck the allocator (R3/R4/R7)
void dkvb_kernel(const float* __restrict__ emb,
                 const float* __restrict__ keys,
                 const float* __restrict__ values,
                 float* __restrict__ out) {
    __shared__ float xs[64][D_CB];   // 2 KB

    const int bid  = blockIdx.x;
    const int c    = bid & 255;      // codebook; bid and bid+256 share an XCD (256%8==0)
    const int h    = bid >> 8;       // tuple half: 0 -> tuples 0..63, 1 -> 64..127
    const int tid  = threadIdx.x;
    const int wave = tid >> 6;
    const int lane = tid & 63;

    // ---- stage this block's 64 tuples of x into LDS (one element/thread) ----
    // x[t][j] = emb[(t>>4)*32768 + c*128 + j*16 + (t&15)]
    {
        const int tl = tid >> 3, j = tid & 7;
        const int tg = h * 64 + tl;
        xs[tl][j] = emb[(size_t)(tg >> 4) * 32768 + c * 128 + j * 16 + (tg & 15)];
    }
    __syncthreads();

    // ---- x' = -2*x, tuple-PAIRED into VGPR float2s: xp[u][j] = (x'[2u][j], x'[2u+1][j]) ----
    v2f xp[4][8];
    #pragma unroll
    for (int u = 0; u < 4; ++u) {
        #pragma unroll
        for (int j = 0; j < 8; ++j) {
            v2f p;
            p.x = -2.0f * xs[wave * TPW + 2 * u][j];
            p.y = -2.0f * xs[wave * TPW + 2 * u + 1][j];
            xp[u][j] = p;
        }
    }

    float bestd[TPW];
    int   besti[TPW];
    #pragma unroll
    for (int t = 0; t < TPW; ++t) { bestd[t] = 3.4028235e38f; besti[t] = 0; }

    // ---- all 8 waves scan the SAME code stream in lockstep (L1 reuse) ----
    // dist' = k2 + sum x'_j k_j  (argmin-equivalent to the full distance)
    const v2f* kb2 = (const v2f*)(keys + (size_t)c * K_CODES * D_CB);
    const int o = lane * 4;          // 4 float2 = one 8-float key row per lane
    v2f a0 = kb2[o], a1 = kb2[o + 1], a2 = kb2[o + 2], a3 = kb2[o + 3];
    for (int ch = 0; ch < CHUNKS; ++ch) {
        const int nco = ((ch + 1 < CHUNKS) ? (ch + 1) : ch) * 256 + o;
        const v2f b0 = kb2[nco];
        const v2f b1 = kb2[nco + 1];
        const v2f b2 = kb2[nco + 2];
        const v2f b3 = kb2[nco + 3];

        const int code = ch * 64 + lane;
        float k2 = a0.x * a0.x;
        k2 = fmaf(a0.y, a0.y, k2);
        k2 = fmaf(a1.x, a1.x, k2);
        k2 = fmaf(a1.y, a1.y, k2);
        k2 = fmaf(a2.x, a2.x, k2);
        k2 = fmaf(a2.y, a2.y, k2);
        k2 = fmaf(a3.x, a3.x, k2);
        k2 = fmaf(a3.y, a3.y, k2);
        v2f k2p; k2p.x = k2; k2p.y = k2;

        #pragma unroll
        for (int u = 0; u < 4; ++u) {
            v2f d;
            PK_INIT(d, xp[u][0], a0, k2p);   // d = x0'*k0 + k2 (both halves)
            PK_HI (d, xp[u][1], a0);
            PK_LO (d, xp[u][2], a1);
            PK_HI (d, xp[u][3], a1);
            PK_LO (d, xp[u][4], a2);
            PK_HI (d, xp[u][5], a2);
            PK_LO (d, xp[u][6], a3);
            PK_HI (d, xp[u][7], a3);

            const int t0 = 2 * u, t1 = 2 * u + 1;
            const bool lt0 = d.x < bestd[t0];
            bestd[t0] = lt0 ? d.x : bestd[t0];
            besti[t0] = lt0 ? code : besti[t0];
            const bool lt1 = d.y < bestd[t1];
            bestd[t1] = lt1 ? d.y : bestd[t1];
            besti[t1] = lt1 ? code : besti[t1];
        }
        a0 = b0; a1 = b1; a2 = b2; a3 = b3;

        // keep the 8 waves within one L1 window; raw s_barrier leaves prefetch in flight
        if ((ch & 3) == 3) __builtin_amdgcn_s_barrier();
    }

    // ---- cross-lane argmin per tuple (tie -> smaller index == numpy) ----
    int myidx = 0;
    #pragma unroll
    for (int t = 0; t < TPW; ++t) {
        float d = bestd[t];
        int   i = besti[t];
        #pragma unroll
        for (int m = 32; m >= 1; m >>= 1) {
            const float od = __shfl_xor(d, m, 64);
            const int   oi = __shfl_xor(i, m, 64);
            if (od < d || (od == d && oi < i)) { d = od; i = oi; }
        }
        if (lane == t) myidx = i;
    }

    // ---- gather values row + scatter to output ----
    if (lane < TPW) {
        const int tg = h * 64 + wave * TPW + lane;   // tuple = b*16 + n
        const int b = tg >> 4, n = tg & 15;
        const float4* vr = (const float4*)(values + ((size_t)c * K_CODES + myidx) * D_CB);
        const float4 v0 = vr[0];
        const float4 v1 = vr[1];
        float* op = out + (size_t)b * 32768 + c * 128 + n;
        op[0]   = v0.x; op[16]  = v0.y; op[32]  = v0.z; op[48]  = v0.w;
        op[64]  = v1.x; op[80]  = v1.y; op[96]  = v1.z; op[112] = v1.w;
    }
}

extern "C" void kernel_launch(void* const* d_in, const int* in_sizes, int n_in,
                              void* d_out, int out_size, void* d_ws, size_t ws_size,
                              hipStream_t stream) {
    const float* emb    = (const float*)d_in[0];
    const float* keys   = (const float*)d_in[1];
    const float* values = (const float*)d_in[2];
    float* out = (float*)d_out;
    dkvb_kernel<<<2 * C_NUM, THREADS, 0, stream>>>(emb, keys, values, out);
}